// Round 3
// baseline (37.753 us; speedup 1.0000x reference)
//
#include <hip/hip_runtime.h>

#define NQ 8
#define NL 4
#define BATCH 8192

// readfirstlane for float (wave-uniform values -> SGPR, frees VGPRs)
__device__ __forceinline__ float rfl(float v) {
    return __int_as_float(__builtin_amdgcn_readfirstlane(__float_as_int(v)));
}

// One sample per 64-lane wave: lane bit (5-i) = wire i for i=0..5;
// register bit k1 = wire 6, k0 = wire 7. State: 4 complex amps = 8 VGPRs.
__global__ __launch_bounds__(256, 8) void qsim(const float* __restrict__ x,
                                               const float* __restrict__ w,
                                               float* __restrict__ out)
{
    const int l   = threadIdx.x & 63;
    const int grp = __builtin_amdgcn_readfirstlane(blockIdx.x * 4 + (threadIdx.x >> 6));
    const float* xr = x + grp * NQ;   // wave-uniform row -> s_load

    // per-lane signs for lane-bit wires 0..5 (bit set -> +1)
    float sgn[6];
    #pragma unroll
    for (int i = 0; i < 6; ++i) sgn[i] = (l & (32 >> i)) ? 1.0f : -1.0f;

    // ---- encoding: real product state ----
    float re[4], im[4];
    {
        float Pg = 1.0f;
        #pragma unroll
        for (int i = 0; i < 6; ++i) {
            float a = 0.5f * (xr[i] + w[2 * i]);   // theta = x + weights[0,i,0]
            float c = __cosf(a), s = __sinf(a);
            Pg *= ((l >> (5 - i)) & 1) ? s : c;
        }
        float a6 = 0.5f * (xr[6] + w[12]);
        float a7 = 0.5f * (xr[7] + w[14]);
        float c6 = __cosf(a6), s6 = __sinf(a6);
        float c7 = __cosf(a7), s7 = __sinf(a7);
        re[0] = Pg * (c6 * c7); re[1] = Pg * (c6 * s7);
        re[2] = Pg * (s6 * c7); re[3] = Pg * (s6 * s7);
        im[0] = im[1] = im[2] = im[3] = 0.0f;
    }

    const int  src = (l ^ (l >> 1)) & 63;   // fused CNOT(0,1)..(4,5) gather source
    const bool c5  = (l & 1);               // wire-5 bit (control of CNOT(5,6))

    #pragma unroll 1
    for (int layer = 0; layer < NL; ++layer) {
        const float* wl = w + layer * (NQ * 2);

        // CNOT(0,1)..(4,5): single lane permutation
        float tr[4], ti[4];
        #pragma unroll
        for (int k = 0; k < 4; ++k) {
            tr[k] = __shfl(re[k], src, 64);
            ti[k] = __shfl(im[k], src, 64);
        }
        // CNOT(5,6) folded with CNOT(6,7) reg-Gray rename:
        // new[k] = tr[(k ^ (k>>1)) ^ (c5 ? 2 : 0)]
        re[0] = c5 ? tr[2] : tr[0];  im[0] = c5 ? ti[2] : ti[0];
        re[1] = c5 ? tr[3] : tr[1];  im[1] = c5 ? ti[3] : ti[1];
        re[2] = c5 ? tr[1] : tr[3];  im[2] = c5 ? ti[1] : ti[3];
        re[3] = c5 ? tr[0] : tr[2];  im[3] = c5 ? ti[0] : ti[2];
        // CNOT(7,0): control = reg bit k0, target = lane bit l5 (xor 32)
        re[1] = __shfl_xor(re[1], 32, 64); im[1] = __shfl_xor(im[1], 32, 64);
        re[3] = __shfl_xor(re[3], 32, 64); im[3] = __shfl_xor(im[3], 32, 64);

        // fused RZ+RY on lane wires 0..5:
        // own coef = (Ar, +-cz), partner coef = (+-sh, -sz), sign by own bit
        #pragma unroll
        for (int i = 0; i < 6; ++i) {
            float c = __cosf(0.5f * wl[2 * i]),     s = __sinf(0.5f * wl[2 * i]);
            float h = __cosf(0.5f * wl[2 * i + 1]), z = __sinf(0.5f * wl[2 * i + 1]);
            float Ar = rfl(c * h), SZ = rfl(s * z);
            float Ai = sgn[i] * rfl(c * z);
            float Br = sgn[i] * rfl(s * h);
            const int m = 32 >> i;
            #pragma unroll
            for (int k = 0; k < 4; ++k) {
                float br = __shfl_xor(re[k], m, 64);
                float bi = __shfl_xor(im[k], m, 64);
                float ar = re[k], ai = im[k];
                re[k] = Ar * ar - Ai * ai + Br * br + SZ * bi;
                im[k] = Ar * ai + Ai * ar + Br * bi - SZ * br;
            }
        }

        // reg wires 6 (bit k1) and 7 (bit k0): RZ = diag(1, e^{i phi}), then RY
        #pragma unroll
        for (int i = 0; i < 2; ++i) {
            float cy = rfl(__cosf(0.5f * wl[12 + 2 * i]));
            float sy = rfl(__sinf(0.5f * wl[12 + 2 * i]));
            float cf = rfl(__cosf(wl[13 + 2 * i]));
            float sf = rfl(__sinf(wl[13 + 2 * i]));
            const int mk = 2 >> i;
            #pragma unroll
            for (int k = 0; k < 4; ++k) {
                if (!(k & mk)) continue;
                float r = re[k], q = im[k];
                re[k] = r * cf - q * sf;
                im[k] = q * cf + r * sf;
            }
            #pragma unroll
            for (int k = 0; k < 4; ++k) {
                if (k & mk) continue;
                int k1 = k | mk;
                float ar = re[k], ai = im[k], br = re[k1], bi = im[k1];
                re[k]  = cy * ar - sy * br;
                im[k]  = cy * ai - sy * bi;
                re[k1] = sy * ar + cy * br;
                im[k1] = sy * ai + cy * bi;
            }
        }
    }

    // ---- measurement ----
    float pv0 = re[0] * re[0] + im[0] * im[0];
    float pv1 = re[1] * re[1] + im[1] * im[1];
    float pv2 = re[2] * re[2] + im[2] * im[2];
    float pv3 = re[3] * re[3] + im[3] * im[3];
    float psum = (pv0 + pv1) + (pv2 + pv3);
    float m6   = (pv0 + pv1) - (pv2 + pv3);   // wire 6: sign by k1
    float m7   = (pv0 - pv1) + (pv2 - pv3);   // wire 7: sign by k0

    // branched Walsh reduce: S and all six lane-wire signed sums in 21 shuffles
    float D[6];
    float v = psum;
    #pragma unroll
    for (int i = 0; i < 6; ++i) {
        float p = __shfl_xor(v, 32 >> i, 64);
        D[i] = v - p;      // signed branch (valid at lanes with bit_i = 0)
        v = v + p;         // running full sum
    }
    #pragma unroll
    for (int i = 0; i < 6; ++i) {
        #pragma unroll
        for (int j = i + 1; j < 6; ++j)
            D[i] += __shfl_xor(D[i], 32 >> j, 64);
    }
    #pragma unroll
    for (int j = 0; j < 6; ++j) {
        m6 += __shfl_xor(m6, 32 >> j, 64);
        m7 += __shfl_xor(m7, 32 >> j, 64);
    }

    if (l == 0) {
        float4* o = (float4*)(out + grp * NQ);
        o[0] = make_float4(D[0], D[1], D[2], D[3]);
        o[1] = make_float4(D[4], D[5], m6, m7);
    }
}

extern "C" void kernel_launch(void* const* d_in, const int* in_sizes, int n_in,
                              void* d_out, int out_size, void* d_ws, size_t ws_size,
                              hipStream_t stream)
{
    const float* x = (const float*)d_in[0];
    const float* w = (const float*)d_in[1];
    float* out = (float*)d_out;
    dim3 block(256);
    dim3 grid((BATCH * 64) / 256);   // 2048 blocks; one wave per sample
    qsim<<<grid, block, 0, stream>>>(x, w, out);
}